// Round 2
// baseline (2572.202 us; speedup 1.0000x reference)
//
#include <hip/hip_runtime.h>
#include <math.h>

#define Ee   200
#define Hh   128
#define G4   512          // 4*H
#define Kk   24
#define Bb   64
#define Tt   1024
#define HIDd 256
#define NEGf (-10000.0f)

// ---------------------------------------------------------------------------
// K0: Wt[d][k][n] = W_ih_d[n][k]   (d<2, k<200, n<512)  -- 204,800 floats
// ---------------------------------------------------------------------------
__global__ __launch_bounds__(256) void k_wt(const float* __restrict__ Wf,
                                            const float* __restrict__ Wb,
                                            float* __restrict__ Wt) {
    int idx = blockIdx.x * 256 + threadIdx.x;
    if (idx >= 2 * Ee * G4) return;
    int d = idx / (Ee * G4);
    int r = idx - d * (Ee * G4);
    int n = r & 511;
    int k = r >> 9;
    const float* W = d ? Wb : Wf;
    Wt[idx] = W[n * Ee + k];
}

// ---------------------------------------------------------------------------
// K1: chunked fused gather+GEMM.
//   For dir d, chunk-local step i (0..CT-1), batch b:
//     t = d ? Tt-1-(c0T+i) : c0T+i
//     Uc[d][i][b][n] = emb[sent[b][t]] . Wt[d][:,n]      (n < 512)
// ---------------------------------------------------------------------------
#define BM 128
#define BN 128
#define BK 8
__global__ __launch_bounds__(256) void k_gemm(const int* __restrict__ sent,
                                              const float* __restrict__ emb,
                                              const float* __restrict__ Wt,
                                              float* __restrict__ Uc,
                                              int c0T, int CT) {
    __shared__ float As[BK][BM];
    __shared__ float Bs[BK][BN];
    __shared__ int   toks[BM];

    int tid = threadIdx.x;
    int n0  = blockIdx.x * BN;         // 0..384 (512 cols per dir)
    int m0  = blockIdx.y * BM;         // row within (i,b) space of this dir
    int d   = blockIdx.z;
    int ty  = tid >> 4, tx = tid & 15;

    if (tid < BM) {
        int m = m0 + tid;
        int i = m >> 6, b = m & 63;
        int t = d ? (Tt - 1 - (c0T + i)) : (c0T + i);
        toks[tid] = sent[b * Tt + t];
    }
    __syncthreads();

    int am  = tid & 127;      // A row in tile
    int ak4 = tid >> 7;       // 0/1 -> k offset 0/4
    int bk  = tid >> 5;       // 0..7
    int bn4 = tid & 31;       // col/4

    const float* aptr = emb + (size_t)toks[am] * Ee + ak4 * 4;
    const float* bptr = Wt + (size_t)d * Ee * G4 + (size_t)bk * G4 + n0 + bn4 * 4;

    float acc[8][8];
#pragma unroll
    for (int i = 0; i < 8; ++i)
#pragma unroll
        for (int j = 0; j < 8; ++j) acc[i][j] = 0.f;

    for (int kc = 0; kc < Ee; kc += BK) {
        float4 av = *(const float4*)(aptr + kc);
        float4 bv = *(const float4*)(bptr + (size_t)kc * G4);
        As[ak4 * 4 + 0][am] = av.x;
        As[ak4 * 4 + 1][am] = av.y;
        As[ak4 * 4 + 2][am] = av.z;
        As[ak4 * 4 + 3][am] = av.w;
        *(float4*)(&Bs[bk][bn4 * 4]) = bv;
        __syncthreads();
#pragma unroll
        for (int k = 0; k < BK; ++k) {
            float a_[8], b_[8];
            *(float4*)&a_[0] = *(const float4*)&As[k][ty * 8];
            *(float4*)&a_[4] = *(const float4*)&As[k][ty * 8 + 4];
            *(float4*)&b_[0] = *(const float4*)&Bs[k][tx * 8];
            *(float4*)&b_[4] = *(const float4*)&Bs[k][tx * 8 + 4];
#pragma unroll
            for (int i = 0; i < 8; ++i)
#pragma unroll
                for (int j = 0; j < 8; ++j)
                    acc[i][j] = fmaf(a_[i], b_[j], acc[i][j]);
        }
        __syncthreads();
    }

    float* base = Uc + ((size_t)d * CT * 64) * G4;
#pragma unroll
    for (int i = 0; i < 8; ++i) {
        float* dst = base + (size_t)(m0 + ty * 8 + i) * G4 + n0 + tx * 8;
        *(float4*)dst       = make_float4(acc[i][0], acc[i][1], acc[i][2], acc[i][3]);
        *(float4*)(dst + 4) = make_float4(acc[i][4], acc[i][5], acc[i][6], acc[i][7]);
    }
}

// ---------------------------------------------------------------------------
// K2: LSTM recurrence chunk + fused hidden2tag partial feats.
//   128 blocks = (dir, batch), 512 threads (one per gate row).
//   pf[d][b][t][k] = h_d(t,b) . W_out[k][d*128 : d*128+128]
// ---------------------------------------------------------------------------
__global__ __launch_bounds__(512) void k_lstm(const float* __restrict__ Uc,
                                              const float* __restrict__ Whh_f,
                                              const float* __restrict__ Whh_b,
                                              const float* __restrict__ bih_f,
                                              const float* __restrict__ bhh_f,
                                              const float* __restrict__ bih_b,
                                              const float* __restrict__ bhh_b,
                                              const float* __restrict__ h0,
                                              const float* __restrict__ c0,
                                              const float* __restrict__ Wout,
                                              float* __restrict__ hst,
                                              float* __restrict__ cst,
                                              float* __restrict__ pf,
                                              int c0T, int CT, int first) {
    __shared__ float hsh[Hh];
    __shared__ float gsh[G4];
    __shared__ float Wsh[Kk][Hh];

    int tid = threadIdx.x;          // gate index 0..511
    int b   = blockIdx.x & 63;
    int d   = blockIdx.x >> 6;

    const float* Whh = d ? Whh_b : Whh_f;
    float bias = d ? (bih_b[tid] + bhh_b[tid]) : (bih_f[tid] + bhh_f[tid]);

    for (int idx = tid; idx < Kk * Hh; idx += 512) {
        int k = idx >> 7, j = idx & 127;
        Wsh[k][j] = Wout[k * HIDd + d * Hh + j];
    }

    float4 w[32];
#pragma unroll
    for (int j = 0; j < 32; ++j)
        w[j] = *(const float4*)(Whh + (size_t)tid * Hh + j * 4);

    float c = 0.f;
    if (tid < Hh) {
        int si = (d * Bb + b) * Hh + tid;
        hsh[tid] = first ? h0[si] : hst[si];
        c        = first ? c0[si] : cst[si];
    }
    __syncthreads();

    const float* Ub = Uc + ((size_t)d * CT * 64 + b) * G4;
    float ucur = Ub[tid];

    for (int i = 0; i < CT; ++i) {
        float unext = (i + 1 < CT) ? Ub[(size_t)(i + 1) * (64 * G4) + tid] : 0.f;

        float a0 = bias + ucur, a1 = 0.f, a2 = 0.f, a3 = 0.f;
        const float4* h4 = (const float4*)hsh;
#pragma unroll
        for (int j4 = 0; j4 < 32; ++j4) {
            float4 hv = h4[j4];
            float4 wv = w[j4];
            a0 = fmaf(wv.x, hv.x, a0);
            a1 = fmaf(wv.y, hv.y, a1);
            a2 = fmaf(wv.z, hv.z, a2);
            a3 = fmaf(wv.w, hv.w, a3);
        }
        gsh[tid] = (a0 + a1) + (a2 + a3);
        __syncthreads();

        if (tid < Hh) {
            float gi = 1.f / (1.f + expf(-gsh[tid]));
            float gf = 1.f / (1.f + expf(-gsh[Hh + tid]));
            float gg = tanhf(gsh[2 * Hh + tid]);
            float go = 1.f / (1.f + expf(-gsh[3 * Hh + tid]));
            c = gf * c + gi * gg;
            hsh[tid] = go * tanhf(c);
        }
        __syncthreads();

        if (tid < 192) {                     // 24 tags x 8 lanes
            int k = tid >> 3, sub = tid & 7;
            const float* hp = hsh + sub * 16;
            const float* wp = &Wsh[k][sub * 16];
            float s0 = 0.f, s1 = 0.f, s2 = 0.f, s3 = 0.f;
#pragma unroll
            for (int j = 0; j < 16; j += 4) {
                s0 = fmaf(hp[j],     wp[j],     s0);
                s1 = fmaf(hp[j + 1], wp[j + 1], s1);
                s2 = fmaf(hp[j + 2], wp[j + 2], s2);
                s3 = fmaf(hp[j + 3], wp[j + 3], s3);
            }
            float s = (s0 + s1) + (s2 + s3);
            s += __shfl_xor(s, 1);
            s += __shfl_xor(s, 2);
            s += __shfl_xor(s, 4);
            if (sub == 0) {
                int t = d ? (Tt - 1 - (c0T + i)) : (c0T + i);
                pf[(((size_t)(d * Bb + b)) * Tt + t) * Kk + k] = s;
            }
        }
        ucur = unext;
    }

    if (tid < Hh) {                  // own hsh[tid] written by this thread
        int si = (d * Bb + b) * Hh + tid;
        hst[si] = hsh[tid];
        cst[si] = c;
    }
}

// ---------------------------------------------------------------------------
// K3: Viterbi forward + backtrace. One block (1 wave) per batch element.
//   feats[b][t][k] = pf_fwd + pf_bwd + b_out[k]  computed on the fly.
// ---------------------------------------------------------------------------
__global__ __launch_bounds__(64) void k_viterbi(const float* __restrict__ pf,
                                                const float* __restrict__ bout,
                                                const float* __restrict__ trans,
                                                float* __restrict__ out) {
    __shared__ unsigned char bptr[Tt * Kk];
    __shared__ float vsh[2][32];
    __shared__ float tsh[32];
    __shared__ unsigned char path[Tt];

    int lane = threadIdx.x;
    int b    = blockIdx.x;

    float tr[Kk];
    float bo = 0.f;
    if (lane < Kk) {
#pragma unroll
        for (int p = 0; p < Kk; ++p) tr[p] = trans[lane * Kk + p]; // [next][prev]
        bo = bout[lane];
        vsh[0][lane] = (lane == 0) ? 0.f : NEGf;                   // START=0
    }
    __syncthreads();

    const float* p0 = pf + ((size_t)b * Tt) * Kk;
    const float* p1 = pf + ((size_t)(Bb + b) * Tt) * Kk;

    for (int t = 0; t < Tt; ++t) {
        int cur = t & 1;
        if (lane < Kk) {
            float feat = p0[t * Kk + lane] + p1[t * Kk + lane] + bo;
            float best = vsh[cur][0] + tr[0];
            int   bp   = 0;
#pragma unroll
            for (int p = 1; p < Kk; ++p) {
                float s = vsh[cur][p] + tr[p];
                if (s > best) { best = s; bp = p; }   // strict >: first-max
            }
            vsh[cur ^ 1][lane] = best + feat;
            bptr[t * Kk + lane] = (unsigned char)bp;
        }
        __syncthreads();
    }

    if (lane < Kk) tsh[lane] = vsh[Tt & 1][lane] + trans[1 * Kk + lane]; // STOP=1
    __syncthreads();

    if (lane == 0) {
        float best = tsh[0];
        int tag = 0;
        for (int n = 1; n < Kk; ++n)
            if (tsh[n] > best) { best = tsh[n]; tag = n; }
        out[b] = best;
        for (int t = Tt - 1; t >= 1; --t) {
            path[t] = (unsigned char)tag;
            tag = bptr[t * Kk + tag];
        }
        path[0] = (unsigned char)tag;
    }
    __syncthreads();

    float* otag = out + Bb + (size_t)b * Tt;
    for (int t = lane; t < Tt; t += 64) otag[t] = (float)path[t];
}

// ---------------------------------------------------------------------------
// host launcher — workspace-adaptive time chunking
//   ws floats: Wt 204800 | pf 3145728 | hst 16384 | cst 16384 | Uc 2*CT*64*512
//   CT=64 needs 30.3 MB; CT=1024 needs 93.5 MB.
// ---------------------------------------------------------------------------
extern "C" void kernel_launch(void* const* d_in, const int* in_sizes, int n_in,
                              void* d_out, int out_size, void* d_ws, size_t ws_size,
                              hipStream_t stream) {
    const int*   sent  = (const int*)d_in[0];
    const float* emb   = (const float*)d_in[2];
    const float* Wih_f = (const float*)d_in[3];
    const float* Whh_f = (const float*)d_in[4];
    const float* bih_f = (const float*)d_in[5];
    const float* bhh_f = (const float*)d_in[6];
    const float* Wih_b = (const float*)d_in[7];
    const float* Whh_b = (const float*)d_in[8];
    const float* bih_b = (const float*)d_in[9];
    const float* bhh_b = (const float*)d_in[10];
    const float* h0    = (const float*)d_in[11];
    const float* c0    = (const float*)d_in[12];
    const float* Wout  = (const float*)d_in[13];
    const float* bout  = (const float*)d_in[14];
    const float* trans = (const float*)d_in[15];

    const size_t fixedf = 204800 + 3145728 + 16384 + 16384;
    int CT = 64;
    const int cands[4] = {1024, 512, 256, 128};
    for (int ci = 0; ci < 4; ++ci) {
        size_t need = (fixedf + (size_t)2 * cands[ci] * 64 * G4) * 4;
        if (need <= ws_size) { CT = cands[ci]; break; }
    }

    float* ws  = (float*)d_ws;
    float* Wt  = ws;
    float* pf  = Wt + 204800;
    float* hst = pf + 3145728;
    float* cst = hst + 16384;
    float* Uc  = cst + 16384;
    float* outf = (float*)d_out;

    k_wt<<<(2 * Ee * G4 + 255) / 256, 256, 0, stream>>>(Wih_f, Wih_b, Wt);

    int NC = Tt / CT;
    for (int cix = 0; cix < NC; ++cix) {
        k_gemm<<<dim3(G4 / BN, CT * 64 / BM, 2), 256, 0, stream>>>(
            sent, emb, Wt, Uc, cix * CT, CT);
        k_lstm<<<128, 512, 0, stream>>>(Uc, Whh_f, Whh_b, bih_f, bhh_f,
                                        bih_b, bhh_b, h0, c0, Wout,
                                        hst, cst, pf, cix * CT, CT, cix == 0);
    }

    k_viterbi<<<Bb, 64, 0, stream>>>(pf, bout, trans, outf);
}

// Round 3
// 1857.329 us; speedup vs baseline: 1.3849x; 1.3849x over previous
//
#include <hip/hip_runtime.h>
#include <math.h>

#define Ee   200
#define Hh   128
#define G4   512          // 4*H
#define Kk   24
#define Bb   64
#define Tt   1024
#define HIDd 256
#define NEGf (-10000.0f)
#define PSTR 9            // partial-sum LDS stride (odd -> conflict-free)

// ---------------------------------------------------------------------------
// K0: Wt[k][n] (k<200, n<1024): n<512 -> W_ih_f[n][k], else W_ih_b[n-512][k]
// ---------------------------------------------------------------------------
__global__ __launch_bounds__(256) void k_wt(const float* __restrict__ Wf,
                                            const float* __restrict__ Wb,
                                            float* __restrict__ Wt) {
    int idx = blockIdx.x * 256 + threadIdx.x;
    if (idx >= Ee * 1024) return;
    int k = idx >> 10, n = idx & 1023;
    Wt[idx] = (n < G4) ? Wf[n * Ee + k] : Wb[(n - G4) * Ee + k];
}

// ---------------------------------------------------------------------------
// K1: fused gather+GEMM, BM=128 BN=256 BK=8.
//   unified=1: one pass, n<1024 spans both dirs, rows m=(t*64+b) global t.
//              Uc[d][t][b][n] with global t for BOTH dirs.
//   unified=0: per-dir (blockIdx.z), chunk-local rows; Uc[d][i][b][n].
// ---------------------------------------------------------------------------
__global__ __launch_bounds__(256, 2) void k_gemm2(const int* __restrict__ sent,
                                                  const float* __restrict__ emb,
                                                  const float* __restrict__ Wt,
                                                  float* __restrict__ Uc,
                                                  int c0T, int CT, int unified) {
    __shared__ float As[8][128];
    __shared__ float Bs[8][256];
    __shared__ int   toks[128];

    int tid = threadIdx.x;
    int n0  = blockIdx.x * 256;
    int m0  = blockIdx.y * 128;
    int dz  = blockIdx.z;
    int ty  = tid >> 4, tx = tid & 15;

    if (tid < 128) {
        int m = m0 + tid;
        int it = m >> 6, b = m & 63;
        int t = unified ? it : (dz ? (Tt - 1 - (c0T + it)) : (c0T + it));
        toks[tid] = sent[b * Tt + t];
    }
    __syncthreads();

    int am = tid & 127, ak4 = tid >> 7;       // A staging
    int brow = tid >> 5, bc4 = tid & 31;      // B staging

    const float* aptr = emb + (size_t)toks[am] * Ee + ak4 * 4;
    int bcol0 = (unified ? 0 : dz * G4) + n0;
    const float* bptr = Wt + (size_t)brow * 1024 + bcol0 + bc4 * 4;

    float acc[8][16];
#pragma unroll
    for (int i = 0; i < 8; ++i)
#pragma unroll
        for (int j = 0; j < 16; ++j) acc[i][j] = 0.f;

    for (int kc = 0; kc < Ee; kc += 8) {
        float4 av  = *(const float4*)(aptr + kc);
        float4 bv0 = *(const float4*)(bptr + (size_t)kc * 1024);
        float4 bv1 = *(const float4*)(bptr + (size_t)kc * 1024 + 128);
        As[ak4 * 4 + 0][am] = av.x;
        As[ak4 * 4 + 1][am] = av.y;
        As[ak4 * 4 + 2][am] = av.z;
        As[ak4 * 4 + 3][am] = av.w;
        *(float4*)&Bs[brow][bc4 * 4]       = bv0;
        *(float4*)&Bs[brow][128 + bc4 * 4] = bv1;
        __syncthreads();
#pragma unroll
        for (int k = 0; k < 8; ++k) {
            float a_[8], b_[16];
            *(float4*)&a_[0] = *(const float4*)&As[k][ty * 8];
            *(float4*)&a_[4] = *(const float4*)&As[k][ty * 8 + 4];
#pragma unroll
            for (int q = 0; q < 4; ++q)     // interleaved cols: tx*4 + 64q (bank-clean)
                *(float4*)&b_[4 * q] = *(const float4*)&Bs[k][tx * 4 + 64 * q];
#pragma unroll
            for (int i = 0; i < 8; ++i)
#pragma unroll
                for (int j = 0; j < 16; ++j)
                    acc[i][j] = fmaf(a_[i], b_[j], acc[i][j]);
        }
        __syncthreads();
    }

    int dd   = unified ? (n0 >> 9) : dz;
    int ncol = unified ? (n0 & 511) : n0;
    float* base = Uc + (size_t)dd * ((size_t)CT * Bb * G4);   // CT==Tt when unified
#pragma unroll
    for (int i = 0; i < 8; ++i) {
        float* dst = base + (size_t)(m0 + ty * 8 + i) * G4 + ncol + tx * 4;
#pragma unroll
        for (int q = 0; q < 4; ++q)
            *(float4*)(dst + 64 * q) = make_float4(acc[i][4 * q], acc[i][4 * q + 1],
                                                   acc[i][4 * q + 2], acc[i][4 * q + 3]);
    }
}

// ---------------------------------------------------------------------------
// K2: LSTM recurrence, column-split GEMV.
//   128 blocks = (dir,b), 512 thr (8 waves). Wave w owns h-cols [16w,16w+16).
//   Lane l holds Whh rows {64i+l} x 16 cols in regs (128 VGPR) + tag row (l<24).
//   P1: partial dots -> ps[row*9+w]   P2: reduce+u+bias+activation -> gsh
//   P3: cell (tid<128) + tag reduce/write of h(i-1) (tid 128..151).
// ---------------------------------------------------------------------------
__global__ __launch_bounds__(512, 2) void k_lstm2(const float* __restrict__ Uc,
                                                  const float* __restrict__ Whh_f,
                                                  const float* __restrict__ Whh_b,
                                                  const float* __restrict__ bih_f,
                                                  const float* __restrict__ bhh_f,
                                                  const float* __restrict__ bih_b,
                                                  const float* __restrict__ bhh_b,
                                                  const float* __restrict__ h0v,
                                                  const float* __restrict__ c0v,
                                                  const float* __restrict__ Wout,
                                                  float* __restrict__ hst,
                                                  float* __restrict__ cst,
                                                  float* __restrict__ pf,
                                                  int c0T, int CT, int first, int unified) {
    __shared__ float hsh[Hh];
    __shared__ float gsh[G4];
    __shared__ float ps[(G4 + Kk) * PSTR];

    int tid  = threadIdx.x;
    int lane = tid & 63, wv = tid >> 6;
    int b = blockIdx.x & 63, d = blockIdx.x >> 6;

    const float* Whh = d ? Whh_b : Whh_f;
    float bias = d ? (bih_b[tid] + bhh_b[tid]) : (bih_f[tid] + bhh_f[tid]);

    float w[8][16];
#pragma unroll
    for (int ri = 0; ri < 8; ++ri) {
        const float* wr = Whh + (size_t)(ri * 64 + lane) * Hh + wv * 16;
#pragma unroll
        for (int c4 = 0; c4 < 4; ++c4)
            *(float4*)&w[ri][c4 * 4] = *(const float4*)(wr + c4 * 4);
    }
    float wt[16];
    if (lane < Kk) {
        const float* wr = Wout + (size_t)lane * HIDd + d * Hh + wv * 16;
#pragma unroll
        for (int c4 = 0; c4 < 4; ++c4)
            *(float4*)&wt[c4 * 4] = *(const float4*)(wr + c4 * 4);
    }

    float cc = 0.f;
    if (tid < Hh) {
        int si = (d * Bb + b) * Hh + tid;
        hsh[tid] = first ? h0v[si] : hst[si];
        cc       = first ? c0v[si] : cst[si];
    }
    __syncthreads();

    const float* Ub = Uc + (size_t)d * ((size_t)CT * Bb * G4);
    int u0 = unified ? (d ? (Tt - 1) : 0) : 0;
    int us = unified ? (d ? -1 : 1) : 1;

    float ucur = Ub[(size_t)u0 * (Bb * G4) + b * G4 + tid];
    float unext = 0.f;

    for (int i = 0; i <= CT; ++i) {
        int last = (i == CT);
        // ---- P1: partial dots off current hsh = h(i-1) ----
        float hv[16];
        *(float4*)&hv[0]  = *(const float4*)&hsh[wv * 16];
        *(float4*)&hv[4]  = *(const float4*)&hsh[wv * 16 + 4];
        *(float4*)&hv[8]  = *(const float4*)&hsh[wv * 16 + 8];
        *(float4*)&hv[12] = *(const float4*)&hsh[wv * 16 + 12];

        if (lane < Kk) {
            float s = 0.f;
#pragma unroll
            for (int c = 0; c < 16; ++c) s = fmaf(wt[c], hv[c], s);
            ps[(G4 + lane) * PSTR + wv] = s;
        }
        if (!last) {
#pragma unroll
            for (int ri = 0; ri < 8; ++ri) {
                float s = 0.f;
#pragma unroll
                for (int c = 0; c < 16; ++c) s = fmaf(w[ri][c], hv[c], s);
                ps[(ri * 64 + lane) * PSTR + wv] = s;
            }
            if (i + 1 < CT)
                unext = Ub[(size_t)(u0 + (i + 1) * us) * (Bb * G4) + b * G4 + tid];
        }
        __syncthreads();

        // ---- P2: reduce + activate (thread tid owns gate tid) ----
        if (!last) {
            const float* pr = ps + (size_t)tid * PSTR;
            float s = ((pr[0] + pr[1]) + (pr[2] + pr[3])) +
                      ((pr[4] + pr[5]) + (pr[6] + pr[7]));
            s += ucur + bias;
            int gt = tid >> 7;                      // 0:i 1:f 2:g 3:o (wave-uniform)
            gsh[tid] = (gt == 2) ? tanhf(s) : 1.f / (1.f + expf(-s));
        }
        __syncthreads();

        // ---- P3: cell + tag emit of h(i-1) ----
        if (!last && tid < Hh) {
            float gi = gsh[tid], gf = gsh[Hh + tid];
            float gg = gsh[2 * Hh + tid], go = gsh[3 * Hh + tid];
            cc = gf * cc + gi * gg;
            hsh[tid] = go * tanhf(cc);
        }
        if (tid >= 128 && tid < 128 + Kk && i >= 1) {
            int k = tid - 128;
            const float* pr = ps + (size_t)(G4 + k) * PSTR;
            float s = ((pr[0] + pr[1]) + (pr[2] + pr[3])) +
                      ((pr[4] + pr[5]) + (pr[6] + pr[7]));
            int tp = c0T + i - 1;
            int tg = d ? (Tt - 1 - tp) : tp;
            pf[((size_t)(d * Bb + b) * Tt + tg) * Kk + k] = s;
        }
        __syncthreads();
        ucur = unext;
    }

    if (tid < Hh) {
        int si = (d * Bb + b) * Hh + tid;
        hst[si] = hsh[tid];
        cst[si] = cc;
    }
}

// ---------------------------------------------------------------------------
// K3: Viterbi. 1 wave per b. v[tag] lives in lane=tag regs; shfl broadcast;
//   24-prev scan split over 2 lane-halves (exact first-max tie semantics).
// ---------------------------------------------------------------------------
__global__ __launch_bounds__(64) void k_viterbi(const float* __restrict__ pf,
                                                const float* __restrict__ bout,
                                                const float* __restrict__ trans,
                                                float* __restrict__ out) {
    __shared__ unsigned char bptr[Tt * Kk];
    __shared__ float tsh[Kk];
    __shared__ unsigned char path[Tt];

    int lane = threadIdx.x;
    int b    = blockIdx.x;
    int half   = (lane >= Kk) ? 1 : 0;
    int n      = half ? (lane - Kk) : lane;       // tag owned by this lane
    int active = (lane < 2 * Kk) && (n < Kk);

    float tr[12];
    float bo = 0.f;
    if (active) {
#pragma unroll
        for (int j = 0; j < 12; ++j) tr[j] = trans[n * Kk + half * 12 + j];
        bo = bout[n];
    }
    float v = (active && half == 0 && n == 0) ? 0.f : NEGf;   // START=0

    const float* p0 = pf + (size_t)b * Tt * Kk;
    const float* p1 = pf + (size_t)(Bb + b) * Tt * Kk;

    for (int t = 0; t < Tt; ++t) {
        float best = NEGf;
        int   bp   = 0;
        if (active) {
            int pb = half * 12;
            best = __shfl(v, pb) + tr[0];
            bp   = pb;
#pragma unroll
            for (int j = 1; j < 12; ++j) {
                float s = __shfl(v, pb + j) + tr[j];
                if (s > best) { best = s; bp = pb + j; }   // strict >: first-max
            }
        }
        float ob  = __shfl(best, n + Kk);
        int   obp = __shfl(bp,   n + Kk);
        if (active && half == 0) {
            if (ob > best) { best = ob; bp = obp; }        // tie -> lower half wins
            float feat = p0[t * Kk + n] + p1[t * Kk + n] + bo;
            v = best + feat;
            bptr[t * Kk + n] = (unsigned char)bp;
        }
    }

    if (half == 0 && lane < Kk) tsh[n] = v + trans[1 * Kk + n];   // STOP=1
    __syncthreads();

    if (lane == 0) {
        float bestv = tsh[0];
        int tag = 0;
        for (int q = 1; q < Kk; ++q)
            if (tsh[q] > bestv) { bestv = tsh[q]; tag = q; }
        out[b] = bestv;
        for (int t = Tt - 1; t >= 1; --t) {
            path[t] = (unsigned char)tag;
            tag = bptr[t * Kk + tag];
        }
        path[0] = (unsigned char)tag;
    }
    __syncthreads();

    float* otag = out + Bb + (size_t)b * Tt;
    for (int t = lane; t < Tt; t += 64) otag[t] = (float)path[t];
}

// ---------------------------------------------------------------------------
// host launcher
// ---------------------------------------------------------------------------
extern "C" void kernel_launch(void* const* d_in, const int* in_sizes, int n_in,
                              void* d_out, int out_size, void* d_ws, size_t ws_size,
                              hipStream_t stream) {
    const int*   sent  = (const int*)d_in[0];
    const float* emb   = (const float*)d_in[2];
    const float* Wih_f = (const float*)d_in[3];
    const float* Whh_f = (const float*)d_in[4];
    const float* bih_f = (const float*)d_in[5];
    const float* bhh_f = (const float*)d_in[6];
    const float* Wih_b = (const float*)d_in[7];
    const float* Whh_b = (const float*)d_in[8];
    const float* bih_b = (const float*)d_in[9];
    const float* bhh_b = (const float*)d_in[10];
    const float* h0    = (const float*)d_in[11];
    const float* c0    = (const float*)d_in[12];
    const float* Wout  = (const float*)d_in[13];
    const float* bout  = (const float*)d_in[14];
    const float* trans = (const float*)d_in[15];

    float* ws  = (float*)d_ws;
    float* Wt  = ws;                       //   204,800 f
    float* pf  = Wt + 204800;              // 3,145,728 f
    float* hst = pf + 3145728;             //    16,384 f
    float* cst = hst + 16384;              //    16,384 f
    float* Uc  = cst + 16384;

    const size_t fixedf = 204800 + 3145728 + 16384 + 16384;
    size_t needU = (size_t)2 * Tt * Bb * G4;
    int unified = ((fixedf + needU) * 4 <= ws_size);

    k_wt<<<(Ee * 1024 + 255) / 256, 256, 0, stream>>>(Wih_f, Wih_b, Wt);

    if (unified) {
        k_gemm2<<<dim3(4, 512, 1), 256, 0, stream>>>(sent, emb, Wt, Uc, 0, Tt, 1);
        k_lstm2<<<128, 512, 0, stream>>>(Uc, Whh_f, Whh_b, bih_f, bhh_f,
                                         bih_b, bhh_b, h0, c0, Wout,
                                         hst, cst, pf, 0, Tt, 1, 1);
    } else {
        int CT = 64;
        const int cands[3] = {512, 256, 128};
        for (int ci = 0; ci < 3; ++ci)
            if ((fixedf + (size_t)2 * cands[ci] * Bb * G4) * 4 <= ws_size) {
                CT = cands[ci]; break;
            }
        int NC = Tt / CT;
        for (int cix = 0; cix < NC; ++cix) {
            k_gemm2<<<dim3(2, CT * 64 / 128, 2), 256, 0, stream>>>(
                sent, emb, Wt, Uc, cix * CT, CT, 0);
            k_lstm2<<<128, 512, 0, stream>>>(Uc, Whh_f, Whh_b, bih_f, bhh_f,
                                             bih_b, bhh_b, h0, c0, Wout,
                                             hst, cst, pf, cix * CT, CT, cix == 0, 0);
        }
    }

    k_viterbi<<<Bb, 64, 0, stream>>>(pf, bout, trans, (float*)d_out);
}